// Round 7
// baseline (413.463 us; speedup 1.0000x reference)
//
#include <hip/hip_runtime.h>
#include <hip/hip_bf16.h>

// CapsNet dynamic routing — fast path. f32 in/out.
// x: [B=32, N=4096, Din=8], W: [N=4096, C=10, Din=8, D=16], out: [B,C,D] f32.
// Algebra (b0=0): iter0 w=1/C; iter1 logits=u_hat.v0; iter2 logits=u_hat.(v0+v1).
// Per pass: recompute u_hat from x+W (L3-resident), block = 8-n chunk, all 32 b.
// Per-block partial sums -> ws, fused reduce+squash kernel (atomic fallback).

#define BB 32
#define NN 4096
#define CC 10
#define DIN 8
#define DD 16
#define NCHUNK 8
#define NBLK (NN / NCHUNK)      // 512
#define TPB 512
#define SOUT (BB * CC * DD)     // 5120

// Wave bq (0..7) handles b = bq*4..bq*4+3. Lane: cq=lane>>4, d=lane&15; c=cq+4r.
// LDS W layout per n-plane: row R=c*16+d holds W[n,c,:,d] (8 floats = 2 float4
// units h=0,1) at swizzled unit index U=(2R+h)^((R>>2)&7)  -> conflict-free b128.
template<int UNIFORM, int PARTIALS>
__global__ __launch_bounds__(TPB, 4) void caps_pass(
    const float* __restrict__ xg,
    const float* __restrict__ Wg,
    const float* __restrict__ vprev,   // [B,C,D] (ignored if UNIFORM)
    float* __restrict__ outp)          // PARTIALS: [NBLK][SOUT]; else [SOUT] atomics
{
    __shared__ float Wl[NCHUNK * CC * DIN * DD];  // 10240 f, swizzled [j][R][i]
    __shared__ float ul[BB * NCHUNK * DIN];       // 2048 f, [b][j][i]

    const int t    = threadIdx.x;
    const int lane = t & 63;
    const int bq   = t >> 6;
    const int cq   = lane >> 4;
    const int d    = lane & 15;
    const int n0   = blockIdx.x * NCHUNK;

    // ---- stage u for whole chunk (layout matches global -> straight copy) ----
    {
        float4* ulV = (float4*)ul;
        const float4* xgV = (const float4*)xg;
        ulV[t] = xgV[(size_t)(t >> 4) * (NN * 2) + n0 * 2 + (t & 15)];
    }
    // ---- stage W for 8 planes, transposed + swizzled ----
    {
        const float4* WgV = (const float4*)Wg;
        #pragma unroll
        for (int wi = 0; wi < 5; ++wi) {
            int m4 = t + wi * TPB;              // 0..2559
            int j  = m4 / 320;
            int q  = m4 - j * 320;              // float4 within plane
            int c  = q >> 5, i = (q & 31) >> 2, d0 = (q & 3) << 2;
            float4 v = WgV[(size_t)(n0 + j) * 320 + q];
            const float* vf = (const float*)&v;
            float* plane = Wl + j * 1280;
            int h = i >> 2, wd = i & 3;
            #pragma unroll
            for (int k = 0; k < 4; ++k) {
                int R = c * DD + d0 + k;
                int U = (R * 2 + h) ^ ((R >> 2) & 7);
                plane[U * 4 + wd] = vf[k];
            }
        }
    }
    __syncthreads();

    // hoist vprev (n-independent)
    float vv[4][3];
    if (!UNIFORM) {
        #pragma unroll
        for (int bb = 0; bb < 4; ++bb) {
            int b = bq * 4 + bb;
            #pragma unroll
            for (int r = 0; r < 3; ++r) {
                int c = cq + 4 * r;
                vv[bb][r] = (c < CC) ? vprev[(b * CC + c) * DD + d] : 0.f;
            }
        }
    }

    float acc[4][3];
    #pragma unroll
    for (int bb = 0; bb < 4; ++bb)
        #pragma unroll
        for (int r = 0; r < 3; ++r) acc[bb][r] = 0.f;

    for (int j = 0; j < NCHUNK; ++j) {
        // per-lane W fragment (b-independent)
        float wreg[3][8];
        const float4* planeV = (const float4*)(Wl + j * 1280);
        #pragma unroll
        for (int r = 0; r < 3; ++r) {
            int c = cq + 4 * r;
            if (c < CC) {
                int R  = c * DD + d;
                int sw = (R >> 2) & 7;
                float4 a0 = planeV[(R * 2) ^ sw];
                float4 a1 = planeV[(R * 2 + 1) ^ sw];
                wreg[r][0]=a0.x; wreg[r][1]=a0.y; wreg[r][2]=a0.z; wreg[r][3]=a0.w;
                wreg[r][4]=a1.x; wreg[r][5]=a1.y; wreg[r][6]=a1.z; wreg[r][7]=a1.w;
            } else {
                #pragma unroll
                for (int i = 0; i < 8; ++i) wreg[r][i] = 0.f;
            }
        }

        const float4* ulV4 = (const float4*)ul;
        #pragma unroll
        for (int bb = 0; bb < 4; ++bb) {
            int b = bq * 4 + bb;
            float4 u0 = ulV4[b * 16 + j * 2];       // LDS broadcast (uniform addr)
            float4 u1 = ulV4[b * 16 + j * 2 + 1];
            float uu[8] = {u0.x,u0.y,u0.z,u0.w,u1.x,u1.y,u1.z,u1.w};

            float uh[3];
            #pragma unroll
            for (int r = 0; r < 3; ++r) {
                float s = 0.f;
                #pragma unroll
                for (int i = 0; i < DIN; ++i) s = fmaf(uu[i], wreg[r][i], s);
                uh[r] = s;                           // 0 for c>=CC
            }

            float w0, w1, w2;
            if (UNIFORM) {
                w0 = w1 = w2 = 1.0f / CC;
            } else {
                float dot[3];
                #pragma unroll
                for (int r = 0; r < 3; ++r) dot[r] = uh[r] * vv[bb][r];
                #pragma unroll
                for (int m = 1; m < 16; m <<= 1) {
                    #pragma unroll
                    for (int r = 0; r < 3; ++r)
                        dot[r] += __shfl_xor(dot[r], m, 64);
                }
                float lmax = fmaxf(dot[0], dot[1]);
                if (cq < 2) lmax = fmaxf(lmax, dot[2]);
                lmax = fmaxf(lmax, __shfl_xor(lmax, 16, 64));
                lmax = fmaxf(lmax, __shfl_xor(lmax, 32, 64));
                float e0 = __expf(dot[0] - lmax);
                float e1 = __expf(dot[1] - lmax);
                float e2 = (cq < 2) ? __expf(dot[2] - lmax) : 0.f;
                float den = e0 + e1 + e2;
                den += __shfl_xor(den, 16, 64);
                den += __shfl_xor(den, 32, 64);
                float inv = __builtin_amdgcn_rcpf(den);
                w0 = e0 * inv; w1 = e1 * inv; w2 = e2 * inv;
            }
            acc[bb][0] = fmaf(w0, uh[0], acc[bb][0]);
            acc[bb][1] = fmaf(w1, uh[1], acc[bb][1]);
            acc[bb][2] = fmaf(w2, uh[2], acc[bb][2]);
        }
    }

    // ---- flush ----
    if (PARTIALS) {
        float* dst = outp + (size_t)blockIdx.x * SOUT;
        #pragma unroll
        for (int bb = 0; bb < 4; ++bb) {
            int b = bq * 4 + bb;
            #pragma unroll
            for (int r = 0; r < 3; ++r) {
                int c = cq + 4 * r;
                if (c < CC) dst[(b * CC + c) * DD + d] = acc[bb][r];  // coalesced
            }
        }
    } else {
        #pragma unroll
        for (int bb = 0; bb < 4; ++bb) {
            int b = bq * 4 + bb;
            #pragma unroll
            for (int r = 0; r < 3; ++r) {
                int c = cq + 4 * r;
                if (c < CC) atomicAdd(&outp[(b * CC + c) * DD + d], acc[bb][r]);
            }
        }
    }
}

// Fused cross-block reduce + squash. Block = one (b,c) row.
// MODE 0: vsum=v ; 1: vsum+=v ; 2: outF=v
template<int MODE>
__global__ __launch_bounds__(256) void caps_reduce(
    const float* __restrict__ part,   // [NBLK][SOUT]
    float* __restrict__ vsum,
    float* __restrict__ outF)
{
    __shared__ float red[256];
    const int row = blockIdx.x;       // b*CC + c
    const int t = threadIdx.x;
    const int d = t & 15, ks = t >> 4;             // 16 k-slices
    const float* p = part + row * DD + d;
    float s = 0.f;
    #pragma unroll 8
    for (int kk = 0; kk < NBLK / 16; ++kk)
        s += p[(size_t)(ks * (NBLK / 16) + kk) * SOUT];
    red[t] = s;
    __syncthreads();
    if (t < 16) {
        float sd = 0.f;
        #pragma unroll
        for (int k2 = 0; k2 < 16; ++k2) sd += red[k2 * 16 + t];
        float s2 = sd * sd;
        #pragma unroll
        for (int m = 1; m < 16; m <<= 1) s2 += __shfl_xor(s2, m, 64);
        float f = s2 / ((1.f + s2) * sqrtf(s2 + 1e-7f));
        float v = f * sd;
        int idx = row * DD + t;
        if (MODE == 0) vsum[idx] = v;
        if (MODE == 1) vsum[idx] += v;
        if (MODE == 2) outF[idx] = v;
    }
}

// Atomic-fallback squash (previous passing structure).
template<int MODE>
__global__ __launch_bounds__(512) void caps_squash(
    const float* __restrict__ sIn,
    float* __restrict__ vsum,
    float* __restrict__ outF)
{
    int r = blockIdx.x * blockDim.x + threadIdx.x;
    if (r >= BB * CC) return;
    const float* p = sIn + (size_t)r * DD;
    float sv[DD]; float s2 = 0.f;
    #pragma unroll
    for (int d = 0; d < DD; ++d) { sv[d] = p[d]; s2 = fmaf(sv[d], sv[d], s2); }
    float f = s2 / ((1.f + s2) * sqrtf(s2 + 1e-7f));
    #pragma unroll
    for (int d = 0; d < DD; ++d) {
        float v = f * sv[d];
        int idx = r * DD + d;
        if (MODE == 0) vsum[idx] = v;
        if (MODE == 1) vsum[idx] += v;
        if (MODE == 2) outF[idx] = v;
    }
}

extern "C" void kernel_launch(void* const* d_in, const int* in_sizes, int n_in,
                              void* d_out, int out_size, void* d_ws, size_t ws_size,
                              hipStream_t stream) {
    const float* x; const float* Wt;
    if (in_sizes[0] == BB * NN * DIN) { x = (const float*)d_in[0]; Wt = (const float*)d_in[1]; }
    else                              { Wt = (const float*)d_in[0]; x = (const float*)d_in[1]; }
    float* out = (float*)d_out;
    float* ws = (float*)d_ws;

    const size_t PART_FLOATS = (size_t)NBLK * SOUT;
    bool partials = ws_size >= (PART_FLOATS + SOUT) * sizeof(float);

    if (partials) {
        float* part = ws;
        float* vsum = ws + PART_FLOATS;
        caps_pass<1,1><<<NBLK, TPB, 0, stream>>>(x, Wt, nullptr, part);
        caps_reduce<0><<<BB*CC, 256, 0, stream>>>(part, vsum, nullptr);
        caps_pass<0,1><<<NBLK, TPB, 0, stream>>>(x, Wt, vsum, part);
        caps_reduce<1><<<BB*CC, 256, 0, stream>>>(part, vsum, nullptr);
        caps_pass<0,1><<<NBLK, TPB, 0, stream>>>(x, Wt, vsum, part);
        caps_reduce<2><<<BB*CC, 256, 0, stream>>>(part, vsum, out);
    } else {
        float* sAcc = ws;
        float* vsum = ws + SOUT;
        hipMemsetAsync(sAcc, 0, SOUT * sizeof(float), stream);
        caps_pass<1,0><<<NBLK, TPB, 0, stream>>>(x, Wt, nullptr, sAcc);
        caps_squash<0><<<1, 512, 0, stream>>>(sAcc, vsum, nullptr);
        hipMemsetAsync(sAcc, 0, SOUT * sizeof(float), stream);
        caps_pass<0,0><<<NBLK, TPB, 0, stream>>>(x, Wt, vsum, sAcc);
        caps_squash<1><<<1, 512, 0, stream>>>(sAcc, vsum, nullptr);
        hipMemsetAsync(sAcc, 0, SOUT * sizeof(float), stream);
        caps_pass<0,0><<<NBLK, TPB, 0, stream>>>(x, Wt, vsum, sAcc);
        caps_squash<2><<<1, 512, 0, stream>>>(sAcc, nullptr, out);
    }
}

// Round 8
// 179.004 us; speedup vs baseline: 2.3098x; 2.3098x over previous
//
#include <hip/hip_runtime.h>
#include <hip/hip_bf16.h>

// CapsNet dynamic routing — fast path v2 (spill fix). f32 in/out.
// x: [B=32, N=4096, Din=8], W: [N=4096, C=10, Din=8, D=16], out: [B,C,D] f32.
// Algebra (b0=0): iter0 w=1/C; iter1 logits=u_hat.v0; iter2 logits=u_hat.(v0+v1).
// Round-7 lesson: __launch_bounds__(512,4) forced VGPR=64 -> scratch spill
// (FETCH 433MB, WRITE 626MB, VALUBusy 2.5%). Fix: no occupancy clamp + phase-split
// inner loop so only one wreg[8] fragment is live at a time.

#define BB 32
#define NN 4096
#define CC 10
#define DIN 8
#define DD 16
#define NCHUNK 8
#define NBLK (NN / NCHUNK)      // 512
#define TPB 512
#define SOUT (BB * CC * DD)     // 5120

// Wave bq (0..7) handles b = bq*4..bq*4+3. Lane: cq=lane>>4, d=lane&15; c=cq+4r.
// LDS W layout per n-plane: row R=c*16+d holds W[n,c,:,d] (8 floats = 2 float4
// units h=0,1) at swizzled unit index U=(2R+h)^((R>>2)&7).
template<int UNIFORM, int PARTIALS>
__global__ __launch_bounds__(TPB) void caps_pass(
    const float* __restrict__ xg,
    const float* __restrict__ Wg,
    const float* __restrict__ vprev,   // [B,C,D] (ignored if UNIFORM)
    float* __restrict__ outp)          // PARTIALS: [NBLK][SOUT]; else [SOUT] atomics
{
    __shared__ float Wl[NCHUNK * CC * DIN * DD];  // 10240 f, swizzled [j][R][i]
    __shared__ float ul[BB * NCHUNK * DIN];       // 2048 f, [b][j][i]

    const int t    = threadIdx.x;
    const int lane = t & 63;
    const int bq   = t >> 6;
    const int cq   = lane >> 4;
    const int d    = lane & 15;
    const int n0   = blockIdx.x * NCHUNK;

    // ---- stage u for whole chunk ----
    {
        float4* ulV = (float4*)ul;
        const float4* xgV = (const float4*)xg;
        ulV[t] = xgV[(size_t)(t >> 4) * (NN * 2) + n0 * 2 + (t & 15)];
    }
    // ---- stage W for 8 planes, transposed + swizzled ----
    {
        const float4* WgV = (const float4*)Wg;
        #pragma unroll
        for (int wi = 0; wi < 5; ++wi) {
            int m4 = t + wi * TPB;              // 0..2559
            int j  = m4 / 320;
            int q  = m4 - j * 320;              // float4 within plane
            int c  = q >> 5, i = (q & 31) >> 2, d0 = (q & 3) << 2;
            float4 v = WgV[(size_t)(n0 + j) * 320 + q];
            const float* vf = (const float*)&v;
            float* plane = Wl + j * 1280;
            int h = i >> 2, wd = i & 3;
            #pragma unroll
            for (int k = 0; k < 4; ++k) {
                int R = c * DD + d0 + k;
                int U = (R * 2 + h) ^ ((R >> 2) & 7);
                plane[U * 4 + wd] = vf[k];
            }
        }
    }
    __syncthreads();

    // hoist vprev (n-independent)
    float vv[4][3];
    if (!UNIFORM) {
        #pragma unroll
        for (int bb = 0; bb < 4; ++bb) {
            int b = bq * 4 + bb;
            #pragma unroll
            for (int r = 0; r < 3; ++r) {
                int c = cq + 4 * r;
                vv[bb][r] = (c < CC) ? vprev[(b * CC + c) * DD + d] : 0.f;
            }
        }
    }

    float acc[4][3];
    #pragma unroll
    for (int bb = 0; bb < 4; ++bb)
        #pragma unroll
        for (int r = 0; r < 3; ++r) acc[bb][r] = 0.f;

    for (int j = 0; j < NCHUNK; ++j) {
        const float4* planeV = (const float4*)(Wl + j * 1280);
        const float4* ulV4   = (const float4*)ul;

        // ---- phase 1: uh[bb][r] — only ONE wreg[8] live at a time ----
        float uh[4][3];
        #pragma unroll
        for (int r = 0; r < 3; ++r) {
            int c = cq + 4 * r;
            float w0=0,w1=0,w2=0,w3=0,w4=0,w5=0,w6=0,w7=0;
            if (c < CC) {
                int R  = c * DD + d;
                int sw = (R >> 2) & 7;
                float4 a0 = planeV[(R * 2) ^ sw];
                float4 a1 = planeV[(R * 2 + 1) ^ sw];
                w0=a0.x; w1=a0.y; w2=a0.z; w3=a0.w;
                w4=a1.x; w5=a1.y; w6=a1.z; w7=a1.w;
            }
            #pragma unroll
            for (int bb = 0; bb < 4; ++bb) {
                int b = bq * 4 + bb;
                float4 u0 = ulV4[b * 16 + j * 2];       // uniform addr: broadcast
                float4 u1 = ulV4[b * 16 + j * 2 + 1];
                float s = 0.f;
                s = fmaf(u0.x, w0, s); s = fmaf(u0.y, w1, s);
                s = fmaf(u0.z, w2, s); s = fmaf(u0.w, w3, s);
                s = fmaf(u1.x, w4, s); s = fmaf(u1.y, w5, s);
                s = fmaf(u1.z, w6, s); s = fmaf(u1.w, w7, s);
                uh[bb][r] = s;                           // 0 for c>=CC
            }
        }

        // ---- phase 2: routing weights + accumulate ----
        #pragma unroll
        for (int bb = 0; bb < 4; ++bb) {
            float w0, w1, w2;
            if (UNIFORM) {
                w0 = w1 = w2 = 1.0f / CC;
            } else {
                float dot[3];
                #pragma unroll
                for (int r = 0; r < 3; ++r) dot[r] = uh[bb][r] * vv[bb][r];
                #pragma unroll
                for (int m = 1; m < 16; m <<= 1) {
                    #pragma unroll
                    for (int r = 0; r < 3; ++r)
                        dot[r] += __shfl_xor(dot[r], m, 64);
                }
                float lmax = fmaxf(dot[0], dot[1]);
                if (cq < 2) lmax = fmaxf(lmax, dot[2]);
                lmax = fmaxf(lmax, __shfl_xor(lmax, 16, 64));
                lmax = fmaxf(lmax, __shfl_xor(lmax, 32, 64));
                float e0 = __expf(dot[0] - lmax);
                float e1 = __expf(dot[1] - lmax);
                float e2 = (cq < 2) ? __expf(dot[2] - lmax) : 0.f;
                float den = e0 + e1 + e2;
                den += __shfl_xor(den, 16, 64);
                den += __shfl_xor(den, 32, 64);
                float inv = __builtin_amdgcn_rcpf(den);
                w0 = e0 * inv; w1 = e1 * inv; w2 = e2 * inv;
            }
            acc[bb][0] = fmaf(w0, uh[bb][0], acc[bb][0]);
            acc[bb][1] = fmaf(w1, uh[bb][1], acc[bb][1]);
            acc[bb][2] = fmaf(w2, uh[bb][2], acc[bb][2]);
        }
    }

    // ---- flush ----
    if (PARTIALS) {
        float* dst = outp + (size_t)blockIdx.x * SOUT;
        #pragma unroll
        for (int bb = 0; bb < 4; ++bb) {
            int b = bq * 4 + bb;
            #pragma unroll
            for (int r = 0; r < 3; ++r) {
                int c = cq + 4 * r;
                if (c < CC) dst[(b * CC + c) * DD + d] = acc[bb][r];  // coalesced
            }
        }
    } else {
        #pragma unroll
        for (int bb = 0; bb < 4; ++bb) {
            int b = bq * 4 + bb;
            #pragma unroll
            for (int r = 0; r < 3; ++r) {
                int c = cq + 4 * r;
                if (c < CC) atomicAdd(&outp[(b * CC + c) * DD + d], acc[bb][r]);
            }
        }
    }
}

// Fused cross-block reduce + squash. Block = one (b,c) row.
// MODE 0: vsum=v ; 1: vsum+=v ; 2: outF=v
template<int MODE>
__global__ __launch_bounds__(256) void caps_reduce(
    const float* __restrict__ part,   // [NBLK][SOUT]
    float* __restrict__ vsum,
    float* __restrict__ outF)
{
    __shared__ float red[256];
    const int row = blockIdx.x;       // b*CC + c
    const int t = threadIdx.x;
    const int d = t & 15, ks = t >> 4;             // 16 k-slices
    const float* p = part + row * DD + d;
    float s = 0.f;
    #pragma unroll 8
    for (int kk = 0; kk < NBLK / 16; ++kk)
        s += p[(size_t)(ks * (NBLK / 16) + kk) * SOUT];
    red[t] = s;
    __syncthreads();
    if (t < 16) {
        float sd = 0.f;
        #pragma unroll
        for (int k2 = 0; k2 < 16; ++k2) sd += red[k2 * 16 + t];
        float s2 = sd * sd;
        #pragma unroll
        for (int m = 1; m < 16; m <<= 1) s2 += __shfl_xor(s2, m, 64);
        float f = s2 / ((1.f + s2) * sqrtf(s2 + 1e-7f));
        float v = f * sd;
        int idx = row * DD + t;
        if (MODE == 0) vsum[idx] = v;
        if (MODE == 1) vsum[idx] += v;
        if (MODE == 2) outF[idx] = v;
    }
}

// Atomic-fallback squash.
template<int MODE>
__global__ __launch_bounds__(512) void caps_squash(
    const float* __restrict__ sIn,
    float* __restrict__ vsum,
    float* __restrict__ outF)
{
    int r = blockIdx.x * blockDim.x + threadIdx.x;
    if (r >= BB * CC) return;
    const float* p = sIn + (size_t)r * DD;
    float sv[DD]; float s2 = 0.f;
    #pragma unroll
    for (int d = 0; d < DD; ++d) { sv[d] = p[d]; s2 = fmaf(sv[d], sv[d], s2); }
    float f = s2 / ((1.f + s2) * sqrtf(s2 + 1e-7f));
    #pragma unroll
    for (int d = 0; d < DD; ++d) {
        float v = f * sv[d];
        int idx = r * DD + d;
        if (MODE == 0) vsum[idx] = v;
        if (MODE == 1) vsum[idx] += v;
        if (MODE == 2) outF[idx] = v;
    }
}

extern "C" void kernel_launch(void* const* d_in, const int* in_sizes, int n_in,
                              void* d_out, int out_size, void* d_ws, size_t ws_size,
                              hipStream_t stream) {
    const float* x; const float* Wt;
    if (in_sizes[0] == BB * NN * DIN) { x = (const float*)d_in[0]; Wt = (const float*)d_in[1]; }
    else                              { Wt = (const float*)d_in[0]; x = (const float*)d_in[1]; }
    float* out = (float*)d_out;
    float* ws = (float*)d_ws;

    const size_t PART_FLOATS = (size_t)NBLK * SOUT;
    bool partials = ws_size >= (PART_FLOATS + SOUT) * sizeof(float);

    if (partials) {
        float* part = ws;
        float* vsum = ws + PART_FLOATS;
        caps_pass<1,1><<<NBLK, TPB, 0, stream>>>(x, Wt, nullptr, part);
        caps_reduce<0><<<BB*CC, 256, 0, stream>>>(part, vsum, nullptr);
        caps_pass<0,1><<<NBLK, TPB, 0, stream>>>(x, Wt, vsum, part);
        caps_reduce<1><<<BB*CC, 256, 0, stream>>>(part, vsum, nullptr);
        caps_pass<0,1><<<NBLK, TPB, 0, stream>>>(x, Wt, vsum, part);
        caps_reduce<2><<<BB*CC, 256, 0, stream>>>(part, vsum, out);
    } else {
        float* sAcc = ws;
        float* vsum = ws + SOUT;
        hipMemsetAsync(sAcc, 0, SOUT * sizeof(float), stream);
        caps_pass<1,0><<<NBLK, TPB, 0, stream>>>(x, Wt, nullptr, sAcc);
        caps_squash<0><<<1, 512, 0, stream>>>(sAcc, vsum, nullptr);
        hipMemsetAsync(sAcc, 0, SOUT * sizeof(float), stream);
        caps_pass<0,0><<<NBLK, TPB, 0, stream>>>(x, Wt, vsum, sAcc);
        caps_squash<1><<<1, 512, 0, stream>>>(sAcc, vsum, nullptr);
        hipMemsetAsync(sAcc, 0, SOUT * sizeof(float), stream);
        caps_pass<0,0><<<NBLK, TPB, 0, stream>>>(x, Wt, vsum, sAcc);
        caps_squash<2><<<1, 512, 0, stream>>>(sAcc, nullptr, out);
    }
}